// Round 1
// baseline (459.303 us; speedup 1.0000x reference)
//
#include <hip/hip_runtime.h>
#include <math.h>

#define BB 2
#define CDIM 256
#define NHEADS 8
#define HD 32
#define HH 40
#define WW 40
#define NN 1600
#define C3 768
#define SCALE 0.17677669529663687f  // 1/sqrt(32)
#define RTE 8            // rows per block, entropy kernel (2 per wave)
#define RTS4 4           // rows per block, sparse kernel (1 wave, 4 rows)
#define TSTR 2048        // tile stride: 32 d * 64 jl
#define HSTR 51200       // per (b,part,h): 25 tiles * 2048

// ---------- helpers ----------
__device__ inline unsigned fkey(float f) {
    unsigned u = __float_as_uint(f);
    return (u & 0x80000000u) ? ~u : (u | 0x80000000u);
}
__device__ inline float finv(unsigned u) {
    unsigned v = (u & 0x80000000u) ? (u ^ 0x80000000u) : ~u;
    return __uint_as_float(v);
}

// ---------- 1x1 conv: 8 output channels per thread ----------
__global__ __launch_bounds__(256) void conv1x1_kernel(const float* __restrict__ x,
                                                      const float* __restrict__ w,
                                                      const float* __restrict__ bias,
                                                      float* __restrict__ out) {
    int blk = blockIdx.x;
    int st = blk % 7;
    int t2 = blk / 7;
    int ocg = t2 % (C3 / 8);
    int b = t2 / (C3 / 8);
    int s = st * 256 + threadIdx.x;
    if (s >= NN) return;
    int oc0 = ocg * 8;
    const float* xb = x + (size_t)b * CDIM * NN + s;
    const float* w0 = w + (size_t)oc0 * CDIM;
    float a[8];
#pragma unroll
    for (int i = 0; i < 8; i++) a[i] = bias[oc0 + i];
#pragma unroll 4
    for (int ic = 0; ic < CDIM; ic++) {
        float xv = xb[(size_t)ic * NN];
#pragma unroll
        for (int i = 0; i < 8; i++) a[i] += w0[i * CDIM + ic] * xv;
    }
    float* ob = out + ((size_t)b * C3 + oc0) * NN + s;
#pragma unroll
    for (int i = 0; i < 8; i++) ob[(size_t)i * NN] = a[i];
}

// ---------- depthwise 3x3 pad1; writes j-tiled layout [b][part][h][kt][d][jl] ----------
__global__ __launch_bounds__(256) void dwconv_kernel(const float* __restrict__ in,
                                                     const float* __restrict__ w,
                                                     const float* __restrict__ bias,
                                                     float* __restrict__ out_t) {
    int idx = blockIdx.x * 256 + threadIdx.x;
    int s = idx % NN;
    int t = idx / NN;
    int c = t % C3;
    int b = t / C3;
    int y = s / WW, xx = s % WW;
    const float* ib = in + ((size_t)b * C3 + c) * NN;
    const float* wr = w + (size_t)c * 9;
    float acc = bias[c];
#pragma unroll
    for (int ky = 0; ky < 3; ky++) {
        int iy = y + ky - 1;
        if (iy < 0 || iy >= HH) continue;
#pragma unroll
        for (int kx = 0; kx < 3; kx++) {
            int ix = xx + kx - 1;
            if (ix < 0 || ix >= WW) continue;
            acc += wr[ky * 3 + kx] * ib[iy * WW + ix];
        }
    }
    int part = c >> 8;
    int r = c & 255;
    int hh = r >> 5;
    int d = r & 31;
    out_t[((size_t)(b * 3 + part) * NHEADS + hh) * HSTR + (s >> 6) * TSTR + d * 64 + (s & 63)] = acc;
}

// ---------- phase 1: streaming entropy on tiled layout (r8 structure) ----------
__global__ __launch_bounds__(256) void entropy_kernel(const float* __restrict__ qkv_t,
                                                      float* __restrict__ ent) {
    int blk = blockIdx.x;      // bh*(NN/RTE) + rt
    int rt = blk % (NN / RTE);
    int bh = blk / (NN / RTE);
    int h = bh % NHEADS, b = bh / NHEADS;
    int row0 = rt * RTE;
    __shared__ float Qs[RTE][HD];
    int tid = threadIdx.x;
    const float* qt = qkv_t + ((size_t)(b * 3 + 0) * NHEADS + h) * HSTR;
    const float* ktb = qkv_t + ((size_t)(b * 3 + 1) * NHEADS + h) * HSTR;
    {
        int r = tid >> 5, d = tid & 31;
        int row = row0 + r;
        Qs[r][d] = qt[(row >> 6) * TSTR + d * 64 + (row & 63)];
    }
    __syncthreads();
    int w = tid >> 6, lane = tid & 63;
    int lr0 = 2 * w, lr1 = lr0 + 1;
    float q0[HD], q1[HD];
#pragma unroll
    for (int d = 0; d < HD; d++) { q0[d] = Qs[lr0][d]; q1[d] = Qs[lr1][d]; }
    float S0 = 0.f, T0 = 0.f, S1 = 0.f, T1 = 0.f;
#pragma unroll 1
    for (int kt = 0; kt < 25; kt++) {
        const float* kp = ktb + kt * TSTR + lane;
        float a0 = 0.f, a1 = 0.f;
#pragma unroll
        for (int dc = 0; dc < 4; dc++) {
            float kc[8];
#pragma unroll
            for (int i = 0; i < 8; i++) kc[i] = kp[(dc * 8 + i) * 64];
#pragma unroll
            for (int i = 0; i < 8; i++) {
                a0 += q0[dc * 8 + i] * kc[i];
                a1 += q1[dc * 8 + i] * kc[i];
            }
        }
        a0 *= SCALE; a1 *= SCALE;
        float e0 = __expf(a0), e1 = __expf(a1);
        S0 += e0; T0 += e0 * a0;
        S1 += e1; T1 += e1 * a1;
    }
#pragma unroll
    for (int o = 1; o < 64; o <<= 1) {
        S0 += __shfl_xor(S0, o); T0 += __shfl_xor(T0, o);
        S1 += __shfl_xor(S1, o); T1 += __shfl_xor(T1, o);
    }
    if (lane == 0) {
        ent[(size_t)bh * NN + row0 + lr0] = logf(S0) - T0 / S0;
        ent[(size_t)bh * NN + row0 + lr1] = logf(S1) - T1 / S1;
    }
}

// ---------- gate ----------
__global__ void gate_kernel(const float* __restrict__ ent_rows,
                            const float* __restrict__ g1w, const float* __restrict__ g1b,
                            const float* __restrict__ g2w, const float* __restrict__ g2b,
                            int* __restrict__ keep) {
    int bh = blockIdx.x;
    int tid = threadIdx.x;
    __shared__ float red[4];
    float ls = 0.f;
    for (int j = tid; j < NN; j += 256) ls += ent_rows[bh * NN + j];
    for (int o = 32; o > 0; o >>= 1) ls += __shfl_down(ls, o);
    int lane = tid & 63, wid = tid >> 6;
    if (lane == 0) red[wid] = ls;
    __syncthreads();
    if (tid == 0) {
        float ent = (red[0] + red[1] + red[2] + red[3]) / (float)NN;
        float val = g2b[0];
#pragma unroll
        for (int j = 0; j < 16; j++) {
            float hid = ent * g1w[j] + g1b[j];
            if (hid < 0.f) hid = 0.f;
            val += hid * g2w[j];
        }
        float ratio = 0.9f / (1.f + expf(-val)) + 0.1f;
        int kp = (int)ceilf(ratio * (float)NN);
        if (kp < 1) kp = 1;
        if (kp > NN) kp = NN;
        keep[bh] = kp;
    }
}

// ---------- phase 2: 4 rows per wave; K/V swept once per 4 rows, reg-prefetched ----------

// one QK^T tile step: prefetch next K tile into NXT while doing FMAs with CUR
#define QKT_STEP(KT, CUR, NXT)                                                 \
    {                                                                          \
        int ktn = ((KT) + 1 < 25) ? (KT) + 1 : 24;                             \
        const float* kq = ktb + ktn * TSTR + lane;                             \
        _Pragma("unroll")                                                      \
        for (int d = 0; d < HD; d++) NXT[d] = kq[d * 64];                      \
        float a0 = 0.f, a1 = 0.f, a2 = 0.f, a3 = 0.f;                          \
        _Pragma("unroll")                                                      \
        for (int d = 0; d < HD; d++) {                                         \
            float kv = CUR[d];                                                 \
            a0 += q0[d] * kv; a1 += q1[d] * kv;                                \
            a2 += q2[d] * kv; a3 += q3[d] * kv;                                \
        }                                                                      \
        a0 *= SCALE; a1 *= SCALE; a2 *= SCALE; a3 *= SCALE;                    \
        int j = (KT) * 64 + lane;                                              \
        att[0][j] = a0; att[1][j] = a1; att[2][j] = a2; att[3][j] = a3;        \
        m0 = fmaxf(m0, a0); m1 = fmaxf(m1, a1);                                \
        m2 = fmaxf(m2, a2); m3 = fmaxf(m3, a3);                                \
    }

// one PV tile step: prefetch next V tile into NXT while doing FMAs with CUR
#define PV_STEP(KT, CUR, NXT)                                                  \
    {                                                                          \
        int ktn = ((KT) + 1 < 25) ? (KT) + 1 : 24;                             \
        const float* vq = vtb + ktn * TSTR + lane;                             \
        _Pragma("unroll")                                                      \
        for (int d = 0; d < HD; d++) NXT[d] = vq[d * 64];                      \
        int j = (KT) * 64 + lane;                                              \
        float a0 = att[0][j], a1 = att[1][j], a2 = att[2][j], a3 = att[3][j];  \
        float p0 = (a0 >= kth0) ? __expf(a0 - m0) : 0.f;                       \
        float p1 = (a1 >= kth1) ? __expf(a1 - m1) : 0.f;                       \
        float p2 = (a2 >= kth2) ? __expf(a2 - m2) : 0.f;                       \
        float p3 = (a3 >= kth3) ? __expf(a3 - m3) : 0.f;                       \
        S0 += p0; S1 += p1; S2 += p2; S3 += p3;                                \
        _Pragma("unroll")                                                      \
        for (int d = 0; d < HD; d++) {                                         \
            float vv = CUR[d];                                                 \
            acc0[d] += p0 * vv; acc1[d] += p1 * vv;                            \
            acc2[d] += p2 * vv; acc3[d] += p3 * vv;                            \
        }                                                                      \
    }

__global__ __launch_bounds__(64) void sparse_attn_kernel(const float* __restrict__ qkv_t,
                                                         const int* __restrict__ keep,
                                                         float* __restrict__ oht) {
    int blk = blockIdx.x;
    int rt = blk % (NN / RTS4);
    int bh = blk / (NN / RTS4);
    int h = bh % NHEADS, b = bh / NHEADS;
    int row0 = rt * RTS4;
    __shared__ float att[RTS4][NN];      // 25.6 KB
    __shared__ unsigned hist[2][256];    // 2 KB
    __shared__ float Qs[RTS4][HD];       // 0.5 KB
    int tid = threadIdx.x;               // 0..63, one wave
    const float* qt = qkv_t + ((size_t)(b * 3 + 0) * NHEADS + h) * HSTR;
    const float* ktb = qkv_t + ((size_t)(b * 3 + 1) * NHEADS + h) * HSTR;
    const float* vtb = qkv_t + ((size_t)(b * 3 + 2) * NHEADS + h) * HSTR;
#pragma unroll
    for (int i = tid; i < RTS4 * HD; i += 64) {
        int r = i >> 5, d = i & 31;
        int row = row0 + r;
        Qs[r][d] = qt[(row >> 6) * TSTR + d * 64 + (row & 63)];
    }
    int want0 = keep[bh];
    __syncthreads();
    int lane = tid;
    float q0[HD], q1[HD], q2[HD], q3[HD];
#pragma unroll
    for (int d = 0; d < HD; d++) {
        q0[d] = Qs[0][d]; q1[d] = Qs[1][d]; q2[d] = Qs[2][d]; q3[d] = Qs[3][d];
    }

    // ---- QK^T into LDS att rows; track per-row max; ping-pong K prefetch ----
    float m0 = -1e30f, m1 = -1e30f, m2 = -1e30f, m3 = -1e30f;
    float kcA[HD], kcB[HD];
    {
        const float* kp0 = ktb + lane;
#pragma unroll
        for (int d = 0; d < HD; d++) kcA[d] = kp0[d * 64];
    }
#pragma unroll 1
    for (int kt = 0; kt < 24; kt += 2) {
        QKT_STEP(kt, kcA, kcB);
        QKT_STEP(kt + 1, kcB, kcA);
    }
    QKT_STEP(24, kcA, kcB);
#pragma unroll
    for (int off = 1; off < 64; off <<= 1) {
        m0 = fmaxf(m0, __shfl_xor(m0, off));
        m1 = fmaxf(m1, __shfl_xor(m1, off));
        m2 = fmaxf(m2, __shfl_xor(m2, off));
        m3 = fmaxf(m3, __shfl_xor(m3, off));
    }

    // ---- radix select kth-largest, two row-pair batches (proven r8 structure) ----
    int l = lane & 31;
    int r = lane >> 5;                   // 0 or 1 within the pair
    float kth0, kth1, kth2, kth3;
#pragma unroll 1
    for (int b2 = 0; b2 < 2; b2++) {
        int rowr = 2 * b2 + r;
        unsigned kvr[50];
#pragma unroll
        for (int k2 = 0; k2 < 50; k2++) kvr[k2] = fkey(att[rowr][k2 * 32 + l]);
        int want = want0;
        unsigned prefixHigh = 0;
        for (int pass = 0; pass < 4; pass++) {
            int shift = 24 - 8 * pass;
#pragma unroll
            for (int i = 0; i < 8; i++) hist[r][248 - 8 * l + i] = 0u;
#pragma unroll
            for (int k2 = 0; k2 < 50; k2++) {
                unsigned u = kvr[k2];
                bool ok = (pass == 0) || ((u >> (shift + 8)) == prefixHigh);
                if (ok) atomicAdd(&hist[r][(u >> shift) & 255u], 1u);
            }
            unsigned sch = 0;
#pragma unroll
            for (int i = 0; i < 8; i++) sch += hist[r][248 - 8 * l + i];
            unsigned inc = sch;
#pragma unroll
            for (int dlt = 1; dlt < 32; dlt <<= 1) {
                unsigned tv = __shfl_up(inc, dlt, 32);
                if (l >= dlt) inc += tv;
            }
            unsigned pref = inc - sch;
            bool found = (pref < (unsigned)want) && ((unsigned)want <= inc);
            int bsel = -1, wnew = 0;
            if (found) {
                unsigned want2 = (unsigned)want - pref, cum = 0;
#pragma unroll
                for (int i = 0; i < 8; i++) {
                    int bbin = 255 - 8 * l - i;
                    unsigned c = hist[r][bbin];
                    if (bsel < 0 && cum + c >= want2) { bsel = bbin; wnew = (int)(want2 - cum); }
                    cum += c;
                }
            }
            unsigned long long mk = __ballot(found);
            int src = (lane < 32) ? __builtin_ctzll(mk & 0xffffffffULL)
                                  : __builtin_ctzll(mk >> 32) + 32;
            bsel = __shfl(bsel, src);
            want = __shfl(wnew, src);
            prefixHigh = (prefixHigh << 8) | (unsigned)bsel;
        }
        float kth = finv(prefixHigh);
        if (b2 == 0) {
            kth0 = __shfl(kth, 0);
            kth1 = __shfl(kth, 32);
        } else {
            kth2 = __shfl(kth, 0);
            kth3 = __shfl(kth, 32);
        }
    }

    // ---- fused sparse softmax + PV (S accumulated inline); ping-pong V prefetch ----
    float acc0[HD], acc1[HD], acc2[HD], acc3[HD];
#pragma unroll
    for (int d = 0; d < HD; d++) { acc0[d] = 0.f; acc1[d] = 0.f; acc2[d] = 0.f; acc3[d] = 0.f; }
    float S0 = 0.f, S1 = 0.f, S2 = 0.f, S3 = 0.f;
    float vcA[HD], vcB[HD];
    {
        const float* vp0 = vtb + lane;
#pragma unroll
        for (int d = 0; d < HD; d++) vcA[d] = vp0[d * 64];
    }
#pragma unroll 1
    for (int kt = 0; kt < 24; kt += 2) {
        PV_STEP(kt, vcA, vcB);
        PV_STEP(kt + 1, vcB, vcA);
    }
    PV_STEP(24, vcA, vcB);
#pragma unroll
    for (int off = 1; off < 64; off <<= 1) {
        S0 += __shfl_xor(S0, off);
        S1 += __shfl_xor(S1, off);
        S2 += __shfl_xor(S2, off);
        S3 += __shfl_xor(S3, off);
    }

    // ---- reduce acc over the 64 lanes via LDS scratch (reuses att rows) ----
    float* scratch = &att[0][0];  // 6400 floats; need 64*33=2112
    int dd = lane & 31;
    int jb = (lane < 32) ? 0 : 32;
#pragma unroll
    for (int d = 0; d < HD; d++) scratch[lane * 33 + d] = acc0[d];
    float sum0 = 0.f;
#pragma unroll
    for (int jj = 0; jj < 32; jj++) sum0 += scratch[(jb + jj) * 33 + dd];
    sum0 += __shfl_xor(sum0, 32);
#pragma unroll
    for (int d = 0; d < HD; d++) scratch[lane * 33 + d] = acc1[d];
    float sum1 = 0.f;
#pragma unroll
    for (int jj = 0; jj < 32; jj++) sum1 += scratch[(jb + jj) * 33 + dd];
    sum1 += __shfl_xor(sum1, 32);
#pragma unroll
    for (int d = 0; d < HD; d++) scratch[lane * 33 + d] = acc2[d];
    float sum2 = 0.f;
#pragma unroll
    for (int jj = 0; jj < 32; jj++) sum2 += scratch[(jb + jj) * 33 + dd];
    sum2 += __shfl_xor(sum2, 32);
#pragma unroll
    for (int d = 0; d < HD; d++) scratch[lane * 33 + d] = acc3[d];
    float sum3 = 0.f;
#pragma unroll
    for (int jj = 0; jj < 32; jj++) sum3 += scratch[(jb + jj) * 33 + dd];
    sum3 += __shfl_xor(sum3, 32);

    if (lane < 32) {
        size_t base = ((size_t)b * CDIM + h * HD + dd) * NN + row0;
        oht[base + 0] = sum0 / S0;
        oht[base + 1] = sum1 / S1;
        oht[base + 2] = sum2 / S2;
        oht[base + 3] = sum3 / S3;
    }
}

// ---------- output projection from oht [b][c][n]: 8 oc per thread ----------
__global__ __launch_bounds__(256) void proj_kernel(const float* __restrict__ oht,
                                                   const float* __restrict__ pw,
                                                   const float* __restrict__ pb,
                                                   float* __restrict__ out) {
    int blk = blockIdx.x;
    int st = blk % 7;
    int t2 = blk / 7;
    int ocg = t2 % (CDIM / 8);
    int b = t2 / (CDIM / 8);
    int s = st * 256 + threadIdx.x;
    if (s >= NN) return;
    int co0 = ocg * 8;
    const float* ib = oht + (size_t)b * CDIM * NN + s;
    const float* w0 = pw + (size_t)co0 * CDIM;
    float a[8];
#pragma unroll
    for (int i = 0; i < 8; i++) a[i] = pb[co0 + i];
#pragma unroll 4
    for (int c = 0; c < CDIM; c++) {
        float xv = ib[(size_t)c * NN];
#pragma unroll
        for (int i = 0; i < 8; i++) a[i] += w0[i * CDIM + c] * xv;
    }
    float* ob = out + ((size_t)b * CDIM + co0) * NN + s;
#pragma unroll
    for (int i = 0; i < 8; i++) ob[(size_t)i * NN] = a[i];
}

extern "C" void kernel_launch(void* const* d_in, const int* in_sizes, int n_in,
                              void* d_out, int out_size, void* d_ws, size_t ws_size,
                              hipStream_t stream) {
    const float* x      = (const float*)d_in[0];
    const float* qkv_w  = (const float*)d_in[1];
    const float* qkv_b  = (const float*)d_in[2];
    const float* pos_w  = (const float*)d_in[3];
    const float* pos_b  = (const float*)d_in[4];
    const float* proj_w = (const float*)d_in[5];
    const float* proj_b = (const float*)d_in[6];
    const float* g1w    = (const float*)d_in[7];
    const float* g1b    = (const float*)d_in[8];
    const float* g2w    = (const float*)d_in[9];
    const float* g2b    = (const float*)d_in[10];
    float* out = (float*)d_out;

    float* ws   = (float*)d_ws;
    float* buf1 = ws;                                  // BB*C3*NN  ([b][c][s])
    float* buf2 = buf1 + (size_t)BB * C3 * NN;         // BB*C3*NN  (j-tiled)
    float* ent  = buf2 + (size_t)BB * C3 * NN;         // BB*NHEADS*NN
    float* oht  = ent + (size_t)BB * NHEADS * NN;      // BB*CDIM*NN  ([b][c][n])
    int* keep   = (int*)(oht + (size_t)BB * CDIM * NN);

    conv1x1_kernel<<<BB * (C3 / 8) * 7, 256, 0, stream>>>(x, qkv_w, qkv_b, buf1);
    dwconv_kernel<<<BB * C3 * NN / 256, 256, 0, stream>>>(buf1, pos_w, pos_b, buf2);
    entropy_kernel<<<NHEADS * BB * (NN / RTE), 256, 0, stream>>>(buf2, ent);
    gate_kernel<<<BB * NHEADS, 256, 0, stream>>>(ent, g1w, g1b, g2w, g2b, keep);
    sparse_attn_kernel<<<NHEADS * BB * (NN / RTS4), 64, 0, stream>>>(buf2, keep, oht);
    proj_kernel<<<BB * (CDIM / 8) * 7, 256, 0, stream>>>(oht, proj_w, proj_b, out);
}